// Round 9
// baseline (394.300 us; speedup 1.0000x reference)
//
#include <hip/hip_runtime.h>

#define NN 50000
#define EE 400000
#define GG 500
#define F_IN 92
#define KP1 96      // F_IN padded to multiple of 32
#define D_H 256
#define D_EMB 128
#define PCH 16      // pool rows per block
#define SCH 49      // scan items per thread (1024*49 >= NN)

typedef __attribute__((ext_vector_type(8))) short short8_t;
typedef __attribute__((ext_vector_type(4))) float floatx4;
typedef unsigned short u16;
typedef unsigned int u32;

__device__ __forceinline__ float lrelu(float v) { return v > 0.f ? v : 0.01f * v; }
__device__ __forceinline__ u16 f2b(float v) {
    union { float f; u32 u; } x; x.f = v;
    u32 r = x.u + 0x7FFFu + ((x.u >> 16) & 1u);   // RNE
    return (u16)(r >> 16);
}
__device__ __forceinline__ float wave_allsum(float v) {
#pragma unroll
    for (int m = 1; m < 64; m <<= 1) v += __shfl_xor(v, m);
    return v;
}

// ---------------- degree count ----------------
__global__ void count_kernel(const int* __restrict__ dst, int* __restrict__ cnt, int E) {
    int e = blockIdx.x * blockDim.x + threadIdx.x;
    if (e < E) atomicAdd(&cnt[dst[e]], 1);
}

// ------- single-block scan: cnt -> exclusive rowptr, + dinv (replaces 4 kernels) -----
__global__ __launch_bounds__(1024) void scan_csr(const int* __restrict__ cnt,
                                                 int* __restrict__ rowptr,
                                                 float* __restrict__ dinv) {
    __shared__ int sums[1024];
    int t = threadIdx.x;
    int base = t * SCH;
    int lim = min(base + SCH, NN);
    int s = 0;
    for (int i = base; i < lim; ++i) s += cnt[i];
    sums[t] = s;
    __syncthreads();
#pragma unroll
    for (int off = 1; off < 1024; off <<= 1) {
        int v = (t >= off) ? sums[t - off] : 0;
        __syncthreads();
        sums[t] += v;
        __syncthreads();
    }
    int run = sums[t] - s;   // exclusive prefix for this thread's chunk
    for (int i = base; i < lim; ++i) {
        int c = cnt[i];
        rowptr[i] = run;
        run += c;
        dinv[i] = rsqrtf((float)c + 1.0f);   // +1 self loop
    }
    if (t == 0) rowptr[NN] = EE;
}

__global__ void scatter_kernel(const int* __restrict__ src, const int* __restrict__ dst,
                               const int* __restrict__ rowptr, int* __restrict__ cursor,
                               int* __restrict__ esrc, int E) {
    int e = blockIdx.x * blockDim.x + threadIdx.x;
    if (e >= E) return;
    int d = dst[e];
    int p = rowptr[d] + atomicAdd(&cursor[d], 1);
    esrc[p] = src[e];
}

// ---------------- all three weight transpose-casts in one kernel ----------------
#define WN_ELEMS (D_H * KP1)      // 24576
#define W1_ELEMS (D_H * D_H)      // 65536
#define W2_ELEMS (D_EMB * D_H)    // 32768
__global__ void cast_all(const float* __restrict__ nfc_W, const float* __restrict__ gc1_W,
                         const float* __restrict__ gc2_W, u16* __restrict__ WtN,
                         u16* __restrict__ Wt1, u16* __restrict__ Wt2) {
    int i = blockIdx.x * blockDim.x + threadIdx.x;
    if (i < WN_ELEMS) {
        int n = i / KP1, k = i % KP1;
        WtN[i] = f2b(k < F_IN ? nfc_W[(long)k * D_H + n] : 0.f);
    } else if (i < WN_ELEMS + W1_ELEMS) {
        int j = i - WN_ELEMS;
        int n = j / D_H, k = j % D_H;
        Wt1[j] = f2b(gc1_W[(long)k * D_H + n]);
    } else if (i < WN_ELEMS + W1_ELEMS + W2_ELEMS) {
        int j = i - WN_ELEMS - W1_ELEMS;
        int n = j / D_H, k = j % D_H;
        Wt2[j] = f2b(gc2_W[(long)k * D_EMB + n]);
    }
}

// ------------- bf16 MFMA GEMM: out[M,Nd] = A[M,K] @ Wt[Nd,K]^T, 128x64 tile -------
// AF32: A is fp32 with row stride Kreal (cols >= Kreal read as zero); else bf16, stride Ka.
template <bool AF32, bool BIAS_ACT, bool ROW_SCALE>
__global__ __launch_bounds__(256) void gemm_mfma(const void* __restrict__ Av,
                                                 const u16* __restrict__ Wt,
                                                 const float* __restrict__ bias,
                                                 const float* __restrict__ rscale,
                                                 u16* __restrict__ out,
                                                 int M, int Ka, int Kreal, int Nd) {
    __shared__ u16 As[128][40];
    __shared__ u16 Bs[64][40];
    int tid = threadIdx.x;
    int wave = tid >> 6, lane = tid & 63;
    int lm = lane & 15, lk = lane >> 4;
    int m0 = blockIdx.x * 128, n0 = blockIdx.y * 64;
    int rowA = tid >> 1, skA = (tid & 1) * 16;
    int rowB = tid >> 2, skB = (tid & 3) * 8;
    int gmA = m0 + rowA;
    const u16* Ab = (const u16*)Av + (AF32 ? 0 : (size_t)gmA * Ka + skA);
    const float* Af = (const float*)Av + (size_t)gmA * Kreal;
    const u16* Bp = Wt + (size_t)(n0 + rowB) * Ka + skB;
    floatx4 acc[2][4] = {};
    for (int k0 = 0; k0 < Ka; k0 += 32) {
        uint4 a0 = make_uint4(0, 0, 0, 0), a1 = make_uint4(0, 0, 0, 0);
        if constexpr (AF32) {
            float f[16];
#pragma unroll
            for (int q = 0; q < 4; ++q) {
                int col = k0 + skA + 4 * q;
                float4 t = make_float4(0.f, 0.f, 0.f, 0.f);
                if (gmA < M && col < Kreal) t = *(const float4*)(Af + col);  // F_IN%4==0
                f[4 * q] = t.x; f[4 * q + 1] = t.y; f[4 * q + 2] = t.z; f[4 * q + 3] = t.w;
            }
            u32 pk[8];
#pragma unroll
            for (int t2 = 0; t2 < 8; ++t2)
                pk[t2] = ((u32)f2b(f[2 * t2 + 1]) << 16) | f2b(f[2 * t2]);
            a0 = make_uint4(pk[0], pk[1], pk[2], pk[3]);
            a1 = make_uint4(pk[4], pk[5], pk[6], pk[7]);
        } else {
            if (gmA < M) {
                a0 = *(const uint4*)(Ab + k0);
                a1 = *(const uint4*)(Ab + k0 + 8);
            }
        }
        uint4 bv = *(const uint4*)(Bp + k0);
        __syncthreads();
        *(uint4*)&As[rowA][skA] = a0;
        *(uint4*)&As[rowA][skA + 8] = a1;
        *(uint4*)&Bs[rowB][skB] = bv;
        __syncthreads();
        short8_t af0 = *(const short8_t*)&As[wave * 32 + lm][lk * 8];
        short8_t af1 = *(const short8_t*)&As[wave * 32 + 16 + lm][lk * 8];
#pragma unroll
        for (int c = 0; c < 4; ++c) {
            short8_t bf = *(const short8_t*)&Bs[c * 16 + lm][lk * 8];
            acc[0][c] = __builtin_amdgcn_mfma_f32_16x16x32_bf16(af0, bf, acc[0][c], 0, 0, 0);
            acc[1][c] = __builtin_amdgcn_mfma_f32_16x16x32_bf16(af1, bf, acc[1][c], 0, 0, 0);
        }
    }
#pragma unroll
    for (int h = 0; h < 2; ++h) {
#pragma unroll
        for (int r = 0; r < 4; ++r) {
            int gm = m0 + wave * 32 + h * 16 + lk * 4 + r;
            if (gm >= M) continue;
            float rs = ROW_SCALE ? rscale[gm] : 1.f;
#pragma unroll
            for (int c = 0; c < 4; ++c) {
                int gn = n0 + c * 16 + lm;
                float v = acc[h][c][r];
                if constexpr (BIAS_ACT) { v += bias[gn]; v = lrelu(v); }
                if constexpr (ROW_SCALE) v *= rs;
                out[(size_t)gm * Nd + gn] = f2b(v);
            }
        }
    }
}

// ------- fused CSR gather + self-loop + LayerNorm + lrelu (+L2): wave/node -------
// Round-7 proven version: wave-uniform row addresses (SGPR base), 8 rows in flight.
template <int U>
__device__ __forceinline__ void loadrow(const u32* __restrict__ p, u32* r) {
    if constexpr (U == 2) { uint2 t = *(const uint2*)p; r[0] = t.x; r[1] = t.y; }
    else                  { r[0] = *p; }
}
template <int D, bool L2N, bool TOBF>
__global__ __launch_bounds__(256) void agg_ln(const u16* __restrict__ y,
                                              const int* __restrict__ rowptr,
                                              const int* __restrict__ esrc,
                                              const float* __restrict__ dinv,
                                              const float* __restrict__ bias,
                                              const float* __restrict__ gamma,
                                              const float* __restrict__ beta,
                                              u16* __restrict__ outb,
                                              float* __restrict__ outf) {
    constexpr int V = D / 64;    // elems per lane (4 / 2)
    constexpr int U = V / 2;     // dwords per lane (2 / 1)
    constexpr int RW = D / 2;    // dwords per row
    int wave = threadIdx.x >> 6, lane = threadIdx.x & 63;
    int i = blockIdx.x * 4 + wave;
    if (i >= NN) return;
    int beg = __builtin_amdgcn_readfirstlane(rowptr[i]);
    int end = __builtin_amdgcn_readfirstlane(rowptr[i + 1]);
    const u32* yu = (const u32*)y;
    const int lu = lane * U;
    float accL[U] = {}, accH[U] = {};
    u32 r[8][U];
    int k = beg;
    for (; k + 7 < end; k += 8) {            // 8 rows in flight (mean degree = 8)
#pragma unroll
        for (int q = 0; q < 8; ++q) loadrow<U>(yu + (size_t)esrc[k + q] * RW + lu, r[q]);
#pragma unroll
        for (int j = 0; j < U; ++j) {
            float sL = 0.f, sH = 0.f;
#pragma unroll
            for (int q = 0; q < 8; ++q) {
                sL += __uint_as_float(r[q][j] << 16);
                sH += __uint_as_float(r[q][j] & 0xFFFF0000u);
            }
            accL[j] += sL; accH[j] += sH;
        }
    }
    for (; k + 3 < end; k += 4) {
#pragma unroll
        for (int q = 0; q < 4; ++q) loadrow<U>(yu + (size_t)esrc[k + q] * RW + lu, r[q]);
#pragma unroll
        for (int j = 0; j < U; ++j) {
            accL[j] += (__uint_as_float(r[0][j] << 16) + __uint_as_float(r[1][j] << 16))
                     + (__uint_as_float(r[2][j] << 16) + __uint_as_float(r[3][j] << 16));
            accH[j] += (__uint_as_float(r[0][j] & 0xFFFF0000u) + __uint_as_float(r[1][j] & 0xFFFF0000u))
                     + (__uint_as_float(r[2][j] & 0xFFFF0000u) + __uint_as_float(r[3][j] & 0xFFFF0000u));
        }
    }
    for (; k < end; ++k) {
        loadrow<U>(yu + (size_t)esrc[k] * RW + lu, r[0]);
#pragma unroll
        for (int j = 0; j < U; ++j) {
            accL[j] += __uint_as_float(r[0][j] << 16);
            accH[j] += __uint_as_float(r[0][j] & 0xFFFF0000u);
        }
    }
    // self loop
    loadrow<U>(yu + (size_t)i * RW + lu, r[0]);
#pragma unroll
    for (int j = 0; j < U; ++j) {
        accL[j] += __uint_as_float(r[0][j] << 16);
        accH[j] += __uint_as_float(r[0][j] & 0xFFFF0000u);
    }
    float di = dinv[i];
    float xv[V], lsum = 0.f;
#pragma unroll
    for (int j = 0; j < U; ++j) {
        xv[2 * j]     = accL[j] * di + bias[lane * V + 2 * j];
        xv[2 * j + 1] = accH[j] * di + bias[lane * V + 2 * j + 1];
    }
#pragma unroll
    for (int v = 0; v < V; ++v) lsum += xv[v];
    float mu = wave_allsum(lsum) * (1.0f / D);
    float l2 = 0.f;
#pragma unroll
    for (int v = 0; v < V; ++v) { xv[v] -= mu; l2 += xv[v] * xv[v]; }
    float rstd = rsqrtf(wave_allsum(l2) * (1.0f / D) + 1e-5f);
    float yv[V], ss = 0.f;
#pragma unroll
    for (int v = 0; v < V; ++v) {
        float t = xv[v] * rstd * gamma[lane * V + v] + beta[lane * V + v];
        t = lrelu(t);
        yv[v] = t; ss += t * t;
    }
    if constexpr (L2N) {
        float inv = 1.0f / fmaxf(sqrtf(wave_allsum(ss)), 1e-12f);
#pragma unroll
        for (int v = 0; v < V; ++v) yv[v] *= inv;
    }
    if constexpr (TOBF) {
        if constexpr (V == 4) {
            *(ushort4*)(outb + (size_t)i * D + lane * V) =
                make_ushort4(f2b(yv[0]), f2b(yv[1]), f2b(yv[2]), f2b(yv[3]));
        } else {
            *(ushort2*)(outb + (size_t)i * D + lane * V) = make_ushort2(f2b(yv[0]), f2b(yv[1]));
        }
    } else {
        if constexpr (V == 2) {
            *(float2*)(outf + (size_t)i * D + lane * V) = make_float2(yv[0], yv[1]);
        } else {
            *(float4*)(outf + (size_t)i * D + lane * V) = make_float4(yv[0], yv[1], yv[2], yv[3]);
        }
    }
}

// ---------- pool stage 1: PCH rows per block, run-flush atomics (batch sorted) -------
__global__ __launch_bounds__(128) void pool_partial(const float* __restrict__ ha,
                                                    const int* __restrict__ batch,
                                                    float* __restrict__ hg) {
    int r0 = blockIdx.x * PCH;
    int f = threadIdx.x;
    int end = min(r0 + PCH, NN);
    int cur = batch[r0];
    float acc = 0.f;
    for (int i = r0; i < end; ++i) {
        int b = batch[i];
        if (b != cur) {
            atomicAdd(&hg[(size_t)cur * D_EMB + f], acc);
            acc = 0.f; cur = b;
        }
        acc += ha[(size_t)i * D_EMB + f];
    }
    atomicAdd(&hg[(size_t)cur * D_EMB + f], acc);
}

// ---------- head MLP: one block (64 threads) per graph on pooled hg ----------
__global__ __launch_bounds__(64) void head_kernel(const float* __restrict__ hg,
                                                  const float* __restrict__ fc1W,
                                                  const float* __restrict__ fc1b,
                                                  const float* __restrict__ fc2W,
                                                  const float* __restrict__ fc2b,
                                                  float* __restrict__ out) {
    int g = blockIdx.x;
    int j = threadIdx.x;  // 0..63
    float h = fc1b[j];
#pragma unroll 8
    for (int k = 0; k < D_EMB; ++k) h += hg[(size_t)g * D_EMB + k] * fc1W[k * 64 + j];
    h = lrelu(h) * fc2W[j];
#pragma unroll
    for (int m = 1; m < 64; m <<= 1) h += __shfl_xor(h, m);
    if (j == 0) out[g] = h + fc2b[0];
}

static inline size_t align256(size_t x) { return (x + 255) & ~(size_t)255; }

extern "C" void kernel_launch(void* const* d_in, const int* in_sizes, int n_in,
                              void* d_out, int out_size, void* d_ws, size_t ws_size,
                              hipStream_t stream) {
    const float* x     = (const float*)d_in[0];
    const int*   ei    = (const int*)d_in[1];
    const int*   batch = (const int*)d_in[2];
    const float* nfc_W = (const float*)d_in[3];
    const float* nfc_b = (const float*)d_in[4];
    const float* gn1_g = (const float*)d_in[5];
    const float* gn1_b = (const float*)d_in[6];
    const float* gc1_W = (const float*)d_in[7];
    const float* gc1_b = (const float*)d_in[8];
    const float* gn2_g = (const float*)d_in[9];
    const float* gn2_b = (const float*)d_in[10];
    const float* gc2_W = (const float*)d_in[11];
    const float* gc2_b = (const float*)d_in[12];
    const float* fc1_W = (const float*)d_in[13];
    const float* fc1_b = (const float*)d_in[14];
    const float* fc2_W = (const float*)d_in[15];
    const float* fc2_b = (const float*)d_in[16];

    char* ws = (char*)d_ws;
    size_t off = 0;
    // cnt + cursor + hg contiguous -> single memset
    int*   cnt    = (int*)(ws + off);   off += (size_t)NN * 4;
    int*   cursor = (int*)(ws + off);   off += (size_t)NN * 4;
    float* hg     = (float*)(ws + off); off += align256((size_t)GG * D_EMB * 4);
    float* dinv   = (float*)(ws + off); off += align256((size_t)NN * 4);
    int*   rowptr = (int*)(ws + off);   off += align256((size_t)(NN + 1) * 4);
    int*   esrc   = (int*)(ws + off);   off += align256((size_t)EE * 4);
    u16*   WtN    = (u16*)(ws + off);   off += align256((size_t)D_H * KP1 * 2);
    u16*   Wt1    = (u16*)(ws + off);   off += align256((size_t)D_H * D_H * 2);
    u16*   Wt2    = (u16*)(ws + off);   off += align256((size_t)D_EMB * D_H * 2);
    u16*   ha1b   = (u16*)(ws + off);   off += align256((size_t)NN * D_H * 2);
    u16*   y1b    = (u16*)(ws + off);   off += align256((size_t)NN * D_H * 2);
    u16*   ha2b   = (u16*)(ws + off);   off += align256((size_t)NN * D_H * 2);
    u16*   y2b    = (u16*)(ws + off);   off += align256((size_t)NN * D_EMB * 2);

    const int* src = ei;
    const int* dst = ei + EE;
    float* out_scores = (float*)d_out;
    float* out_ha     = (float*)d_out + GG;

    const int MB = (NN + 127) / 128;
    const size_t zbytes = (size_t)NN * 8 + (size_t)GG * D_EMB * 4;  // cnt+cursor+hg

    // 1) one memset; CSR build: count -> single-block scan(+dinv) -> scatter
    hipMemsetAsync(cnt, 0, zbytes, stream);
    count_kernel<<<(EE + 255) / 256, 256, 0, stream>>>(dst, cnt, EE);
    scan_csr<<<1, 1024, 0, stream>>>(cnt, rowptr, dinv);
    scatter_kernel<<<(EE + 255) / 256, 256, 0, stream>>>(src, dst, rowptr, cursor, esrc, EE);

    // 2) all weight casts in one kernel (x cast fused into GEMM-1)
    cast_all<<<(WN_ELEMS + W1_ELEMS + W2_ELEMS + 255) / 256, 256, 0, stream>>>(
        nfc_W, gc1_W, gc2_W, WtN, Wt1, Wt2);

    // 3) ha1 = lrelu(x @ nfc_W + b)   [N,256] bf16  (A read as fp32, cast in-register)
    gemm_mfma<true, true, false><<<dim3(MB, D_H / 64), 256, 0, stream>>>(
        x, WtN, nfc_b, nullptr, ha1b, NN, KP1, F_IN, D_H);

    // 4) conv1: y1 = (ha1 @ gc1_W) * dinv[row]; fused agg+LN -> ha2 bf16
    gemm_mfma<false, false, true><<<dim3(MB, D_H / 64), 256, 0, stream>>>(
        ha1b, Wt1, nullptr, dinv, y1b, NN, D_H, D_H, D_H);
    agg_ln<D_H, false, true><<<NN / 4, 256, 0, stream>>>(
        y1b, rowptr, esrc, dinv, gc1_b, gn1_g, gn1_b, ha2b, nullptr);

    // 5) conv2: y2 = (ha2 @ gc2_W) * dinv[row]; fused agg+LN+L2 -> out_ha fp32
    gemm_mfma<false, false, true><<<dim3(MB, D_EMB / 64), 256, 0, stream>>>(
        ha2b, Wt2, nullptr, dinv, y2b, NN, D_H, D_H, D_EMB);
    agg_ln<D_EMB, true, false><<<NN / 4, 256, 0, stream>>>(
        y2b, rowptr, esrc, dinv, gc2_b, gn2_g, gn2_b, nullptr, out_ha);

    // 6) parallel pool + tiny head
    pool_partial<<<(NN + PCH - 1) / PCH, 128, 0, stream>>>(out_ha, batch, hg);
    head_kernel<<<GG, 64, 0, stream>>>(hg, fc1_W, fc1_b, fc2_W, fc2_b, out_scores);
}

// Round 10
// 298.872 us; speedup vs baseline: 1.3193x; 1.3193x over previous
//
#include <hip/hip_runtime.h>

#define NN 50000
#define EE 400000
#define GG 500
#define F_IN 92
#define KP1 96      // F_IN padded to multiple of 32
#define D_H 256
#define D_EMB 128
#define PCH 16      // pool rows per block

typedef __attribute__((ext_vector_type(8))) short short8_t;
typedef __attribute__((ext_vector_type(4))) float floatx4;
typedef unsigned short u16;
typedef unsigned int u32;

__device__ __forceinline__ float lrelu(float v) { return v > 0.f ? v : 0.01f * v; }
__device__ __forceinline__ u16 f2b(float v) {
    union { float f; u32 u; } x; x.f = v;
    u32 r = x.u + 0x7FFFu + ((x.u >> 16) & 1u);   // RNE
    return (u16)(r >> 16);
}
__device__ __forceinline__ float wave_allsum(float v) {
#pragma unroll
    for (int m = 1; m < 64; m <<= 1) v += __shfl_xor(v, m);
    return v;
}

// ---------------- degree count ----------------
__global__ void count_kernel(const int* __restrict__ dst, int* __restrict__ cnt, int E) {
    int e = blockIdx.x * blockDim.x + threadIdx.x;
    if (e < E) atomicAdd(&cnt[dst[e]], 1);
}

// ---------------- 3-kernel exclusive scan -> rowptr (+ fused dinv) ----------------
// NOTE: single-block scan_csr (r9) was 107 µs — latency-serialized on one CU. Keep wide.
__global__ void scan1(const int* __restrict__ cnt, int* __restrict__ excl,
                      int* __restrict__ bsum, float* __restrict__ dinv, int n) {
    __shared__ int sm[256];
    int i = blockIdx.x * 256 + threadIdx.x;
    int v = (i < n) ? cnt[i] : 0;
    if (i < n) dinv[i] = rsqrtf((float)v + 1.0f);   // +1 self loop
    sm[threadIdx.x] = v;
    __syncthreads();
#pragma unroll
    for (int off = 1; off < 256; off <<= 1) {
        int t = (threadIdx.x >= off) ? sm[threadIdx.x - off] : 0;
        __syncthreads();
        sm[threadIdx.x] += t;
        __syncthreads();
    }
    if (i < n) excl[i] = sm[threadIdx.x] - v;
    if (threadIdx.x == 255) bsum[blockIdx.x] = sm[255];
}
__global__ void scan2(int* __restrict__ bsum, int nb) {
    __shared__ int sm[256];
    int v = (threadIdx.x < nb) ? bsum[threadIdx.x] : 0;
    sm[threadIdx.x] = v;
    __syncthreads();
#pragma unroll
    for (int off = 1; off < 256; off <<= 1) {
        int t = (threadIdx.x >= off) ? sm[threadIdx.x - off] : 0;
        __syncthreads();
        sm[threadIdx.x] += t;
        __syncthreads();
    }
    if (threadIdx.x < nb) bsum[threadIdx.x] = sm[threadIdx.x] - v;
}
__global__ void scan3(int* __restrict__ rowptr, const int* __restrict__ bsum, int n, int E) {
    int i = blockIdx.x * 256 + threadIdx.x;
    if (i < n) rowptr[i] += bsum[blockIdx.x];
    if (i == 0) rowptr[n] = E;
}

__global__ void scatter_kernel(const int* __restrict__ src, const int* __restrict__ dst,
                               const int* __restrict__ rowptr, int* __restrict__ cursor,
                               int* __restrict__ esrc, int E) {
    int e = blockIdx.x * blockDim.x + threadIdx.x;
    if (e >= E) return;
    int d = dst[e];
    int p = rowptr[d] + atomicAdd(&cursor[d], 1);
    esrc[p] = src[e];
}

// ---------------- all three weight transpose-casts in one kernel ----------------
#define WN_ELEMS (D_H * KP1)      // 24576
#define W1_ELEMS (D_H * D_H)      // 65536
#define W2_ELEMS (D_EMB * D_H)    // 32768
__global__ void cast_all(const float* __restrict__ nfc_W, const float* __restrict__ gc1_W,
                         const float* __restrict__ gc2_W, u16* __restrict__ WtN,
                         u16* __restrict__ Wt1, u16* __restrict__ Wt2) {
    int i = blockIdx.x * blockDim.x + threadIdx.x;
    if (i < WN_ELEMS) {
        int n = i / KP1, k = i % KP1;
        WtN[i] = f2b(k < F_IN ? nfc_W[(long)k * D_H + n] : 0.f);
    } else if (i < WN_ELEMS + W1_ELEMS) {
        int j = i - WN_ELEMS;
        int n = j / D_H, k = j % D_H;
        Wt1[j] = f2b(gc1_W[(long)k * D_H + n]);
    } else if (i < WN_ELEMS + W1_ELEMS + W2_ELEMS) {
        int j = i - WN_ELEMS - W1_ELEMS;
        int n = j / D_H, k = j % D_H;
        Wt2[j] = f2b(gc2_W[(long)k * D_EMB + n]);
    }
}

// ------------- bf16 MFMA GEMM: out[M,Nd] = A[M,K] @ Wt[Nd,K]^T, 128x64 tile -------
// AF32: A is fp32 with row stride Kreal (cols >= Kreal read as zero); else bf16, stride Ka.
template <bool AF32, bool BIAS_ACT, bool ROW_SCALE>
__global__ __launch_bounds__(256) void gemm_mfma(const void* __restrict__ Av,
                                                 const u16* __restrict__ Wt,
                                                 const float* __restrict__ bias,
                                                 const float* __restrict__ rscale,
                                                 u16* __restrict__ out,
                                                 int M, int Ka, int Kreal, int Nd) {
    __shared__ u16 As[128][40];
    __shared__ u16 Bs[64][40];
    int tid = threadIdx.x;
    int wave = tid >> 6, lane = tid & 63;
    int lm = lane & 15, lk = lane >> 4;
    int m0 = blockIdx.x * 128, n0 = blockIdx.y * 64;
    int rowA = tid >> 1, skA = (tid & 1) * 16;
    int rowB = tid >> 2, skB = (tid & 3) * 8;
    int gmA = m0 + rowA;
    const u16* Ab = (const u16*)Av + (AF32 ? 0 : (size_t)gmA * Ka + skA);
    const float* Af = (const float*)Av + (size_t)gmA * Kreal;
    const u16* Bp = Wt + (size_t)(n0 + rowB) * Ka + skB;
    floatx4 acc[2][4] = {};
    for (int k0 = 0; k0 < Ka; k0 += 32) {
        uint4 a0 = make_uint4(0, 0, 0, 0), a1 = make_uint4(0, 0, 0, 0);
        if constexpr (AF32) {
            float f[16];
#pragma unroll
            for (int q = 0; q < 4; ++q) {
                int col = k0 + skA + 4 * q;
                float4 t = make_float4(0.f, 0.f, 0.f, 0.f);
                if (gmA < M && col < Kreal) t = *(const float4*)(Af + col);  // F_IN%4==0
                f[4 * q] = t.x; f[4 * q + 1] = t.y; f[4 * q + 2] = t.z; f[4 * q + 3] = t.w;
            }
            u32 pk[8];
#pragma unroll
            for (int t2 = 0; t2 < 8; ++t2)
                pk[t2] = ((u32)f2b(f[2 * t2 + 1]) << 16) | f2b(f[2 * t2]);
            a0 = make_uint4(pk[0], pk[1], pk[2], pk[3]);
            a1 = make_uint4(pk[4], pk[5], pk[6], pk[7]);
        } else {
            if (gmA < M) {
                a0 = *(const uint4*)(Ab + k0);
                a1 = *(const uint4*)(Ab + k0 + 8);
            }
        }
        uint4 bv = *(const uint4*)(Bp + k0);
        __syncthreads();
        *(uint4*)&As[rowA][skA] = a0;
        *(uint4*)&As[rowA][skA + 8] = a1;
        *(uint4*)&Bs[rowB][skB] = bv;
        __syncthreads();
        short8_t af0 = *(const short8_t*)&As[wave * 32 + lm][lk * 8];
        short8_t af1 = *(const short8_t*)&As[wave * 32 + 16 + lm][lk * 8];
#pragma unroll
        for (int c = 0; c < 4; ++c) {
            short8_t bf = *(const short8_t*)&Bs[c * 16 + lm][lk * 8];
            acc[0][c] = __builtin_amdgcn_mfma_f32_16x16x32_bf16(af0, bf, acc[0][c], 0, 0, 0);
            acc[1][c] = __builtin_amdgcn_mfma_f32_16x16x32_bf16(af1, bf, acc[1][c], 0, 0, 0);
        }
    }
#pragma unroll
    for (int h = 0; h < 2; ++h) {
#pragma unroll
        for (int r = 0; r < 4; ++r) {
            int gm = m0 + wave * 32 + h * 16 + lk * 4 + r;
            if (gm >= M) continue;
            float rs = ROW_SCALE ? rscale[gm] : 1.f;
#pragma unroll
            for (int c = 0; c < 4; ++c) {
                int gn = n0 + c * 16 + lm;
                float v = acc[h][c][r];
                if constexpr (BIAS_ACT) { v += bias[gn]; v = lrelu(v); }
                if constexpr (ROW_SCALE) v *= rs;
                out[(size_t)gm * Nd + gn] = f2b(v);
            }
        }
    }
}

// ------- fused CSR gather + self-loop + LayerNorm + lrelu (+L2): wave/node -------
// Round-7 proven version: wave-uniform row addresses (SGPR base), 8 rows in flight.
template <int U>
__device__ __forceinline__ void loadrow(const u32* __restrict__ p, u32* r) {
    if constexpr (U == 2) { uint2 t = *(const uint2*)p; r[0] = t.x; r[1] = t.y; }
    else                  { r[0] = *p; }
}
template <int D, bool L2N, bool TOBF>
__global__ __launch_bounds__(256) void agg_ln(const u16* __restrict__ y,
                                              const int* __restrict__ rowptr,
                                              const int* __restrict__ esrc,
                                              const float* __restrict__ dinv,
                                              const float* __restrict__ bias,
                                              const float* __restrict__ gamma,
                                              const float* __restrict__ beta,
                                              u16* __restrict__ outb,
                                              float* __restrict__ outf) {
    constexpr int V = D / 64;    // elems per lane (4 / 2)
    constexpr int U = V / 2;     // dwords per lane (2 / 1)
    constexpr int RW = D / 2;    // dwords per row
    int wave = threadIdx.x >> 6, lane = threadIdx.x & 63;
    int i = blockIdx.x * 4 + wave;
    if (i >= NN) return;
    int beg = __builtin_amdgcn_readfirstlane(rowptr[i]);
    int end = __builtin_amdgcn_readfirstlane(rowptr[i + 1]);
    const u32* yu = (const u32*)y;
    const int lu = lane * U;
    float accL[U] = {}, accH[U] = {};
    u32 r[8][U];
    int k = beg;
    for (; k + 7 < end; k += 8) {            // 8 rows in flight (mean degree = 8)
#pragma unroll
        for (int q = 0; q < 8; ++q) loadrow<U>(yu + (size_t)esrc[k + q] * RW + lu, r[q]);
#pragma unroll
        for (int j = 0; j < U; ++j) {
            float sL = 0.f, sH = 0.f;
#pragma unroll
            for (int q = 0; q < 8; ++q) {
                sL += __uint_as_float(r[q][j] << 16);
                sH += __uint_as_float(r[q][j] & 0xFFFF0000u);
            }
            accL[j] += sL; accH[j] += sH;
        }
    }
    for (; k + 3 < end; k += 4) {
#pragma unroll
        for (int q = 0; q < 4; ++q) loadrow<U>(yu + (size_t)esrc[k + q] * RW + lu, r[q]);
#pragma unroll
        for (int j = 0; j < U; ++j) {
            accL[j] += (__uint_as_float(r[0][j] << 16) + __uint_as_float(r[1][j] << 16))
                     + (__uint_as_float(r[2][j] << 16) + __uint_as_float(r[3][j] << 16));
            accH[j] += (__uint_as_float(r[0][j] & 0xFFFF0000u) + __uint_as_float(r[1][j] & 0xFFFF0000u))
                     + (__uint_as_float(r[2][j] & 0xFFFF0000u) + __uint_as_float(r[3][j] & 0xFFFF0000u));
        }
    }
    for (; k < end; ++k) {
        loadrow<U>(yu + (size_t)esrc[k] * RW + lu, r[0]);
#pragma unroll
        for (int j = 0; j < U; ++j) {
            accL[j] += __uint_as_float(r[0][j] << 16);
            accH[j] += __uint_as_float(r[0][j] & 0xFFFF0000u);
        }
    }
    // self loop
    loadrow<U>(yu + (size_t)i * RW + lu, r[0]);
#pragma unroll
    for (int j = 0; j < U; ++j) {
        accL[j] += __uint_as_float(r[0][j] << 16);
        accH[j] += __uint_as_float(r[0][j] & 0xFFFF0000u);
    }
    float di = dinv[i];
    float xv[V], lsum = 0.f;
#pragma unroll
    for (int j = 0; j < U; ++j) {
        xv[2 * j]     = accL[j] * di + bias[lane * V + 2 * j];
        xv[2 * j + 1] = accH[j] * di + bias[lane * V + 2 * j + 1];
    }
#pragma unroll
    for (int v = 0; v < V; ++v) lsum += xv[v];
    float mu = wave_allsum(lsum) * (1.0f / D);
    float l2 = 0.f;
#pragma unroll
    for (int v = 0; v < V; ++v) { xv[v] -= mu; l2 += xv[v] * xv[v]; }
    float rstd = rsqrtf(wave_allsum(l2) * (1.0f / D) + 1e-5f);
    float yv[V], ss = 0.f;
#pragma unroll
    for (int v = 0; v < V; ++v) {
        float t = xv[v] * rstd * gamma[lane * V + v] + beta[lane * V + v];
        t = lrelu(t);
        yv[v] = t; ss += t * t;
    }
    if constexpr (L2N) {
        float inv = 1.0f / fmaxf(sqrtf(wave_allsum(ss)), 1e-12f);
#pragma unroll
        for (int v = 0; v < V; ++v) yv[v] *= inv;
    }
    if constexpr (TOBF) {
        if constexpr (V == 4) {
            *(ushort4*)(outb + (size_t)i * D + lane * V) =
                make_ushort4(f2b(yv[0]), f2b(yv[1]), f2b(yv[2]), f2b(yv[3]));
        } else {
            *(ushort2*)(outb + (size_t)i * D + lane * V) = make_ushort2(f2b(yv[0]), f2b(yv[1]));
        }
    } else {
        if constexpr (V == 2) {
            *(float2*)(outf + (size_t)i * D + lane * V) = make_float2(yv[0], yv[1]);
        } else {
            *(float4*)(outf + (size_t)i * D + lane * V) = make_float4(yv[0], yv[1], yv[2], yv[3]);
        }
    }
}

// ---------- pool stage 1: PCH rows per block, run-flush atomics (batch sorted) -------
__global__ __launch_bounds__(128) void pool_partial(const float* __restrict__ ha,
                                                    const int* __restrict__ batch,
                                                    float* __restrict__ hg) {
    int r0 = blockIdx.x * PCH;
    int f = threadIdx.x;
    int end = min(r0 + PCH, NN);
    int cur = batch[r0];
    float acc = 0.f;
    for (int i = r0; i < end; ++i) {
        int b = batch[i];
        if (b != cur) {
            atomicAdd(&hg[(size_t)cur * D_EMB + f], acc);
            acc = 0.f; cur = b;
        }
        acc += ha[(size_t)i * D_EMB + f];
    }
    atomicAdd(&hg[(size_t)cur * D_EMB + f], acc);
}

// ---------- head MLP: one block (64 threads) per graph on pooled hg ----------
__global__ __launch_bounds__(64) void head_kernel(const float* __restrict__ hg,
                                                  const float* __restrict__ fc1W,
                                                  const float* __restrict__ fc1b,
                                                  const float* __restrict__ fc2W,
                                                  const float* __restrict__ fc2b,
                                                  float* __restrict__ out) {
    int g = blockIdx.x;
    int j = threadIdx.x;  // 0..63
    float h = fc1b[j];
#pragma unroll 8
    for (int k = 0; k < D_EMB; ++k) h += hg[(size_t)g * D_EMB + k] * fc1W[k * 64 + j];
    h = lrelu(h) * fc2W[j];
#pragma unroll
    for (int m = 1; m < 64; m <<= 1) h += __shfl_xor(h, m);
    if (j == 0) out[g] = h + fc2b[0];
}

static inline size_t align256(size_t x) { return (x + 255) & ~(size_t)255; }

extern "C" void kernel_launch(void* const* d_in, const int* in_sizes, int n_in,
                              void* d_out, int out_size, void* d_ws, size_t ws_size,
                              hipStream_t stream) {
    const float* x     = (const float*)d_in[0];
    const int*   ei    = (const int*)d_in[1];
    const int*   batch = (const int*)d_in[2];
    const float* nfc_W = (const float*)d_in[3];
    const float* nfc_b = (const float*)d_in[4];
    const float* gn1_g = (const float*)d_in[5];
    const float* gn1_b = (const float*)d_in[6];
    const float* gc1_W = (const float*)d_in[7];
    const float* gc1_b = (const float*)d_in[8];
    const float* gn2_g = (const float*)d_in[9];
    const float* gn2_b = (const float*)d_in[10];
    const float* gc2_W = (const float*)d_in[11];
    const float* gc2_b = (const float*)d_in[12];
    const float* fc1_W = (const float*)d_in[13];
    const float* fc1_b = (const float*)d_in[14];
    const float* fc2_W = (const float*)d_in[15];
    const float* fc2_b = (const float*)d_in[16];

    char* ws = (char*)d_ws;
    size_t off = 0;
    // cnt + cursor + hg contiguous -> single memset
    int*   cnt    = (int*)(ws + off);   off += (size_t)NN * 4;
    int*   cursor = (int*)(ws + off);   off += (size_t)NN * 4;
    float* hg     = (float*)(ws + off); off += align256((size_t)GG * D_EMB * 4);
    float* dinv   = (float*)(ws + off); off += align256((size_t)NN * 4);
    int*   rowptr = (int*)(ws + off);   off += align256((size_t)(NN + 1) * 4);
    int*   bsum   = (int*)(ws + off);   off += align256((size_t)256 * 4);
    int*   esrc   = (int*)(ws + off);   off += align256((size_t)EE * 4);
    u16*   WtN    = (u16*)(ws + off);   off += align256((size_t)D_H * KP1 * 2);
    u16*   Wt1    = (u16*)(ws + off);   off += align256((size_t)D_H * D_H * 2);
    u16*   Wt2    = (u16*)(ws + off);   off += align256((size_t)D_EMB * D_H * 2);
    u16*   ha1b   = (u16*)(ws + off);   off += align256((size_t)NN * D_H * 2);
    u16*   y1b    = (u16*)(ws + off);   off += align256((size_t)NN * D_H * 2);
    u16*   ha2b   = (u16*)(ws + off);   off += align256((size_t)NN * D_H * 2);
    u16*   y2b    = (u16*)(ws + off);   off += align256((size_t)NN * D_EMB * 2);

    const int* src = ei;
    const int* dst = ei + EE;
    float* out_scores = (float*)d_out;
    float* out_ha     = (float*)d_out + GG;

    const int NB = (NN + 255) / 256;
    const int MB = (NN + 127) / 128;
    const size_t zbytes = (size_t)NN * 8 + (size_t)GG * D_EMB * 4;  // cnt+cursor+hg

    // 1) one memset; CSR build: count -> wide 3-kernel scan(+dinv) -> scatter
    hipMemsetAsync(cnt, 0, zbytes, stream);
    count_kernel<<<(EE + 255) / 256, 256, 0, stream>>>(dst, cnt, EE);
    scan1<<<NB, 256, 0, stream>>>(cnt, rowptr, bsum, dinv, NN);
    scan2<<<1, 256, 0, stream>>>(bsum, NB);
    scan3<<<NB, 256, 0, stream>>>(rowptr, bsum, NN, EE);
    scatter_kernel<<<(EE + 255) / 256, 256, 0, stream>>>(src, dst, rowptr, cursor, esrc, EE);

    // 2) all weight casts in one kernel (x cast fused into GEMM-1)
    cast_all<<<(WN_ELEMS + W1_ELEMS + W2_ELEMS + 255) / 256, 256, 0, stream>>>(
        nfc_W, gc1_W, gc2_W, WtN, Wt1, Wt2);

    // 3) ha1 = lrelu(x @ nfc_W + b)   [N,256] bf16  (A read as fp32, cast in-register)
    gemm_mfma<true, true, false><<<dim3(MB, D_H / 64), 256, 0, stream>>>(
        x, WtN, nfc_b, nullptr, ha1b, NN, KP1, F_IN, D_H);

    // 4) conv1: y1 = (ha1 @ gc1_W) * dinv[row]; fused agg+LN -> ha2 bf16
    gemm_mfma<false, false, true><<<dim3(MB, D_H / 64), 256, 0, stream>>>(
        ha1b, Wt1, nullptr, dinv, y1b, NN, D_H, D_H, D_H);
    agg_ln<D_H, false, true><<<NN / 4, 256, 0, stream>>>(
        y1b, rowptr, esrc, dinv, gc1_b, gn1_g, gn1_b, ha2b, nullptr);

    // 5) conv2: y2 = (ha2 @ gc2_W) * dinv[row]; fused agg+LN+L2 -> out_ha fp32
    gemm_mfma<false, false, true><<<dim3(MB, D_EMB / 64), 256, 0, stream>>>(
        ha2b, Wt2, nullptr, dinv, y2b, NN, D_H, D_H, D_EMB);
    agg_ln<D_EMB, true, false><<<NN / 4, 256, 0, stream>>>(
        y2b, rowptr, esrc, dinv, gc2_b, gn2_g, gn2_b, nullptr, out_ha);

    // 6) parallel pool + tiny head
    pool_partial<<<(NN + PCH - 1) / PCH, 128, 0, stream>>>(out_ha, batch, hg);
    head_kernel<<<GG, 64, 0, stream>>>(hg, fc1_W, fc1_b, fc2_W, fc2_b, out_scores);
}

// Round 11
// 295.176 us; speedup vs baseline: 1.3358x; 1.0125x over previous
//
#include <hip/hip_runtime.h>

#define NN 50000
#define EE 400000
#define GG 500
#define F_IN 92
#define KP1 96      // F_IN padded to multiple of 32
#define D_H 256
#define D_EMB 128
#define PCH 16      // pool rows per block

typedef __attribute__((ext_vector_type(8))) short short8_t;
typedef __attribute__((ext_vector_type(4))) float floatx4;
typedef unsigned short u16;
typedef unsigned int u32;

__device__ __forceinline__ float lrelu(float v) { return v > 0.f ? v : 0.01f * v; }
__device__ __forceinline__ u16 f2b(float v) {
    union { float f; u32 u; } x; x.f = v;
    u32 r = x.u + 0x7FFFu + ((x.u >> 16) & 1u);   // RNE
    return (u16)(r >> 16);
}
__device__ __forceinline__ float wave_allsum(float v) {
#pragma unroll
    for (int m = 1; m < 64; m <<= 1) v += __shfl_xor(v, m);
    return v;
}
// direct global->LDS DMA, 16 B per lane; LDS dest = wave-uniform base + lane*16
__device__ __forceinline__ void glds16(const void* g, void* l) {
    __builtin_amdgcn_global_load_lds(
        (const __attribute__((address_space(1))) void*)g,
        (__attribute__((address_space(3))) void*)l, 16, 0, 0);
}

// ---------------- degree count ----------------
__global__ void count_kernel(const int* __restrict__ dst, int* __restrict__ cnt, int E) {
    int e = blockIdx.x * blockDim.x + threadIdx.x;
    if (e < E) atomicAdd(&cnt[dst[e]], 1);
}

// ---------------- 3-kernel exclusive scan -> rowptr (+ fused dinv) ----------------
// NOTE: single-block scan_csr (r9) was 107 µs — latency-serialized on one CU. Keep wide.
__global__ void scan1(const int* __restrict__ cnt, int* __restrict__ excl,
                      int* __restrict__ bsum, float* __restrict__ dinv, int n) {
    __shared__ int sm[256];
    int i = blockIdx.x * 256 + threadIdx.x;
    int v = (i < n) ? cnt[i] : 0;
    if (i < n) dinv[i] = rsqrtf((float)v + 1.0f);   // +1 self loop
    sm[threadIdx.x] = v;
    __syncthreads();
#pragma unroll
    for (int off = 1; off < 256; off <<= 1) {
        int t = (threadIdx.x >= off) ? sm[threadIdx.x - off] : 0;
        __syncthreads();
        sm[threadIdx.x] += t;
        __syncthreads();
    }
    if (i < n) excl[i] = sm[threadIdx.x] - v;
    if (threadIdx.x == 255) bsum[blockIdx.x] = sm[255];
}
__global__ void scan2(int* __restrict__ bsum, int nb) {
    __shared__ int sm[256];
    int v = (threadIdx.x < nb) ? bsum[threadIdx.x] : 0;
    sm[threadIdx.x] = v;
    __syncthreads();
#pragma unroll
    for (int off = 1; off < 256; off <<= 1) {
        int t = (threadIdx.x >= off) ? sm[threadIdx.x - off] : 0;
        __syncthreads();
        sm[threadIdx.x] += t;
        __syncthreads();
    }
    if (threadIdx.x < nb) bsum[threadIdx.x] = sm[threadIdx.x] - v;
}
__global__ void scan3(int* __restrict__ rowptr, const int* __restrict__ bsum, int n, int E) {
    int i = blockIdx.x * 256 + threadIdx.x;
    if (i < n) rowptr[i] += bsum[blockIdx.x];
    if (i == 0) rowptr[n] = E;
}

__global__ void scatter_kernel(const int* __restrict__ src, const int* __restrict__ dst,
                               const int* __restrict__ rowptr, int* __restrict__ cursor,
                               int* __restrict__ esrc, int E) {
    int e = blockIdx.x * blockDim.x + threadIdx.x;
    if (e >= E) return;
    int d = dst[e];
    int p = rowptr[d] + atomicAdd(&cursor[d], 1);
    esrc[p] = src[e];
}

// ---------------- all three weight transpose-casts in one kernel ----------------
#define WN_ELEMS (D_H * KP1)      // 24576
#define W1_ELEMS (D_H * D_H)      // 65536
#define W2_ELEMS (D_EMB * D_H)    // 32768
__global__ void cast_all(const float* __restrict__ nfc_W, const float* __restrict__ gc1_W,
                         const float* __restrict__ gc2_W, u16* __restrict__ WtN,
                         u16* __restrict__ Wt1, u16* __restrict__ Wt2) {
    int i = blockIdx.x * blockDim.x + threadIdx.x;
    if (i < WN_ELEMS) {
        int n = i / KP1, k = i % KP1;
        WtN[i] = f2b(k < F_IN ? nfc_W[(long)k * D_H + n] : 0.f);
    } else if (i < WN_ELEMS + W1_ELEMS) {
        int j = i - WN_ELEMS;
        int n = j / D_H, k = j % D_H;
        Wt1[j] = f2b(gc1_W[(long)k * D_H + n]);
    } else if (i < WN_ELEMS + W1_ELEMS + W2_ELEMS) {
        int j = i - WN_ELEMS - W1_ELEMS;
        int n = j / D_H, k = j % D_H;
        Wt2[j] = f2b(gc2_W[(long)k * D_EMB + n]);
    }
}

// ------------- GEMM-1: fp32 A, in-register bf16 cast, VGPR staging, 128x64 tile -------
__global__ __launch_bounds__(256) void gemm_f32a(const float* __restrict__ Af_,
                                                 const u16* __restrict__ Wt,
                                                 const float* __restrict__ bias,
                                                 u16* __restrict__ out,
                                                 int M, int Ka, int Kreal, int Nd) {
    __shared__ u16 As[128][40];
    __shared__ u16 Bs[64][40];
    int tid = threadIdx.x;
    int wave = tid >> 6, lane = tid & 63;
    int lm = lane & 15, lk = lane >> 4;
    int m0 = blockIdx.x * 128, n0 = blockIdx.y * 64;
    int rowA = tid >> 1, skA = (tid & 1) * 16;
    int rowB = tid >> 2, skB = (tid & 3) * 8;
    int gmA = m0 + rowA;
    const float* Af = Af_ + (size_t)gmA * Kreal;
    const u16* Bp = Wt + (size_t)(n0 + rowB) * Ka + skB;
    floatx4 acc[2][4] = {};
    for (int k0 = 0; k0 < Ka; k0 += 32) {
        float f[16];
#pragma unroll
        for (int q = 0; q < 4; ++q) {
            int col = k0 + skA + 4 * q;
            float4 t = make_float4(0.f, 0.f, 0.f, 0.f);
            if (gmA < M && col < Kreal) t = *(const float4*)(Af + col);  // F_IN%4==0
            f[4 * q] = t.x; f[4 * q + 1] = t.y; f[4 * q + 2] = t.z; f[4 * q + 3] = t.w;
        }
        u32 pk[8];
#pragma unroll
        for (int t2 = 0; t2 < 8; ++t2)
            pk[t2] = ((u32)f2b(f[2 * t2 + 1]) << 16) | f2b(f[2 * t2]);
        uint4 bv = *(const uint4*)(Bp + k0);
        __syncthreads();
        *(uint4*)&As[rowA][skA] = make_uint4(pk[0], pk[1], pk[2], pk[3]);
        *(uint4*)&As[rowA][skA + 8] = make_uint4(pk[4], pk[5], pk[6], pk[7]);
        *(uint4*)&Bs[rowB][skB] = bv;
        __syncthreads();
        short8_t af0 = *(const short8_t*)&As[wave * 32 + lm][lk * 8];
        short8_t af1 = *(const short8_t*)&As[wave * 32 + 16 + lm][lk * 8];
#pragma unroll
        for (int c = 0; c < 4; ++c) {
            short8_t bf = *(const short8_t*)&Bs[c * 16 + lm][lk * 8];
            acc[0][c] = __builtin_amdgcn_mfma_f32_16x16x32_bf16(af0, bf, acc[0][c], 0, 0, 0);
            acc[1][c] = __builtin_amdgcn_mfma_f32_16x16x32_bf16(af1, bf, acc[1][c], 0, 0, 0);
        }
    }
#pragma unroll
    for (int h = 0; h < 2; ++h) {
#pragma unroll
        for (int r = 0; r < 4; ++r) {
            int gm = m0 + wave * 32 + h * 16 + lk * 4 + r;
            if (gm >= M) continue;
#pragma unroll
            for (int c = 0; c < 4; ++c) {
                int gn = n0 + c * 16 + lm;
                float v = acc[h][c][r] + bias[gn];
                v = lrelu(v);
                out[(size_t)gm * Nd + gn] = f2b(v);
            }
        }
    }
}

// ------- GEMM-2/3: bf16 A, global_load_lds(16B) staging, unpadded LDS, 128x64 tile ----
// OOB tail rows read into the adjacent ws buffer (valid memory); garbage rows are
// never stored (MFMA C rows depend only on their own A row).
__global__ __launch_bounds__(256) void gemm_glds(const u16* __restrict__ A,
                                                 const u16* __restrict__ Wt,
                                                 const float* __restrict__ rscale,
                                                 u16* __restrict__ out,
                                                 int M, int Ka, int Nd) {
    __shared__ u16 As[128][32];   // unpadded: glds writes base + lane*16B contiguous
    __shared__ u16 Bs[64][32];
    int tid = threadIdx.x;
    int wave = tid >> 6, lane = tid & 63;
    int lm = lane & 15, lk = lane >> 4;
    int m0 = blockIdx.x * 128, n0 = blockIdx.y * 64;
    int lr = lane >> 2;           // 0..15: row within a 16-row chunk
    int lc = (lane & 3) * 8;      // u16 col offset (16 B granules)
    const u16* ApA = A + (size_t)(m0 + wave * 32 + lr) * Ka + lc;
    const u16* ApB = A + (size_t)(m0 + wave * 32 + 16 + lr) * Ka + lc;
    const u16* Bp  = Wt + (size_t)(n0 + wave * 16 + lr) * Ka + lc;
    u16* ldsA0 = &As[wave * 32][0];       // wave-uniform LDS bases
    u16* ldsA1 = &As[wave * 32 + 16][0];
    u16* ldsB  = &Bs[wave * 16][0];
    floatx4 acc[2][4] = {};
    for (int k0 = 0; k0 < Ka; k0 += 32) {
        __syncthreads();                  // prior iter's LDS reads complete
        glds16(ApA + k0, ldsA0);
        glds16(ApB + k0, ldsA1);
        glds16(Bp + k0, ldsB);
        __syncthreads();                  // drains vmcnt: LDS tiles landed
        short8_t af0 = *(const short8_t*)&As[wave * 32 + lm][lk * 8];
        short8_t af1 = *(const short8_t*)&As[wave * 32 + 16 + lm][lk * 8];
#pragma unroll
        for (int c = 0; c < 4; ++c) {
            short8_t bf = *(const short8_t*)&Bs[c * 16 + lm][lk * 8];
            acc[0][c] = __builtin_amdgcn_mfma_f32_16x16x32_bf16(af0, bf, acc[0][c], 0, 0, 0);
            acc[1][c] = __builtin_amdgcn_mfma_f32_16x16x32_bf16(af1, bf, acc[1][c], 0, 0, 0);
        }
    }
#pragma unroll
    for (int h = 0; h < 2; ++h) {
#pragma unroll
        for (int r = 0; r < 4; ++r) {
            int gm = m0 + wave * 32 + h * 16 + lk * 4 + r;
            if (gm >= M) continue;
            float rs = rscale[gm];
#pragma unroll
            for (int c = 0; c < 4; ++c) {
                int gn = n0 + c * 16 + lm;
                out[(size_t)gm * Nd + gn] = f2b(acc[h][c][r] * rs);
            }
        }
    }
}

// ------- fused CSR gather + self-loop + LayerNorm + lrelu (+L2): wave/node -------
// Wave-uniform row addresses (SGPR base), 8 rows in flight. (r8's half-wave split
// regressed: per-lane addressing + stream-merge VALU beat the wider loads.)
template <int U>
__device__ __forceinline__ void loadrow(const u32* __restrict__ p, u32* r) {
    if constexpr (U == 2) { uint2 t = *(const uint2*)p; r[0] = t.x; r[1] = t.y; }
    else                  { r[0] = *p; }
}
template <int D, bool L2N, bool TOBF>
__global__ __launch_bounds__(256) void agg_ln(const u16* __restrict__ y,
                                              const int* __restrict__ rowptr,
                                              const int* __restrict__ esrc,
                                              const float* __restrict__ dinv,
                                              const float* __restrict__ bias,
                                              const float* __restrict__ gamma,
                                              const float* __restrict__ beta,
                                              u16* __restrict__ outb,
                                              float* __restrict__ outf) {
    constexpr int V = D / 64;    // elems per lane (4 / 2)
    constexpr int U = V / 2;     // dwords per lane (2 / 1)
    constexpr int RW = D / 2;    // dwords per row
    int wave = threadIdx.x >> 6, lane = threadIdx.x & 63;
    int i = blockIdx.x * 4 + wave;
    if (i >= NN) return;
    int beg = __builtin_amdgcn_readfirstlane(rowptr[i]);
    int end = __builtin_amdgcn_readfirstlane(rowptr[i + 1]);
    const u32* yu = (const u32*)y;
    const int lu = lane * U;
    float accL[U] = {}, accH[U] = {};
    u32 r[8][U];
    int k = beg;
    for (; k + 7 < end; k += 8) {            // 8 rows in flight (mean degree = 8)
#pragma unroll
        for (int q = 0; q < 8; ++q) loadrow<U>(yu + (size_t)esrc[k + q] * RW + lu, r[q]);
#pragma unroll
        for (int j = 0; j < U; ++j) {
            float sL = 0.f, sH = 0.f;
#pragma unroll
            for (int q = 0; q < 8; ++q) {
                sL += __uint_as_float(r[q][j] << 16);
                sH += __uint_as_float(r[q][j] & 0xFFFF0000u);
            }
            accL[j] += sL; accH[j] += sH;
        }
    }
    for (; k + 3 < end; k += 4) {
#pragma unroll
        for (int q = 0; q < 4; ++q) loadrow<U>(yu + (size_t)esrc[k + q] * RW + lu, r[q]);
#pragma unroll
        for (int j = 0; j < U; ++j) {
            accL[j] += (__uint_as_float(r[0][j] << 16) + __uint_as_float(r[1][j] << 16))
                     + (__uint_as_float(r[2][j] << 16) + __uint_as_float(r[3][j] << 16));
            accH[j] += (__uint_as_float(r[0][j] & 0xFFFF0000u) + __uint_as_float(r[1][j] & 0xFFFF0000u))
                     + (__uint_as_float(r[2][j] & 0xFFFF0000u) + __uint_as_float(r[3][j] & 0xFFFF0000u));
        }
    }
    for (; k < end; ++k) {
        loadrow<U>(yu + (size_t)esrc[k] * RW + lu, r[0]);
#pragma unroll
        for (int j = 0; j < U; ++j) {
            accL[j] += __uint_as_float(r[0][j] << 16);
            accH[j] += __uint_as_float(r[0][j] & 0xFFFF0000u);
        }
    }
    // self loop
    loadrow<U>(yu + (size_t)i * RW + lu, r[0]);
#pragma unroll
    for (int j = 0; j < U; ++j) {
        accL[j] += __uint_as_float(r[0][j] << 16);
        accH[j] += __uint_as_float(r[0][j] & 0xFFFF0000u);
    }
    float di = dinv[i];
    float xv[V], lsum = 0.f;
#pragma unroll
    for (int j = 0; j < U; ++j) {
        xv[2 * j]     = accL[j] * di + bias[lane * V + 2 * j];
        xv[2 * j + 1] = accH[j] * di + bias[lane * V + 2 * j + 1];
    }
#pragma unroll
    for (int v = 0; v < V; ++v) lsum += xv[v];
    float mu = wave_allsum(lsum) * (1.0f / D);
    float l2 = 0.f;
#pragma unroll
    for (int v = 0; v < V; ++v) { xv[v] -= mu; l2 += xv[v] * xv[v]; }
    float rstd = rsqrtf(wave_allsum(l2) * (1.0f / D) + 1e-5f);
    float yv[V], ss = 0.f;
#pragma unroll
    for (int v = 0; v < V; ++v) {
        float t = xv[v] * rstd * gamma[lane * V + v] + beta[lane * V + v];
        t = lrelu(t);
        yv[v] = t; ss += t * t;
    }
    if constexpr (L2N) {
        float inv = 1.0f / fmaxf(sqrtf(wave_allsum(ss)), 1e-12f);
#pragma unroll
        for (int v = 0; v < V; ++v) yv[v] *= inv;
    }
    if constexpr (TOBF) {
        if constexpr (V == 4) {
            *(ushort4*)(outb + (size_t)i * D + lane * V) =
                make_ushort4(f2b(yv[0]), f2b(yv[1]), f2b(yv[2]), f2b(yv[3]));
        } else {
            *(ushort2*)(outb + (size_t)i * D + lane * V) = make_ushort2(f2b(yv[0]), f2b(yv[1]));
        }
    } else {
        if constexpr (V == 2) {
            *(float2*)(outf + (size_t)i * D + lane * V) = make_float2(yv[0], yv[1]);
        } else {
            *(float4*)(outf + (size_t)i * D + lane * V) = make_float4(yv[0], yv[1], yv[2], yv[3]);
        }
    }
}

// ---------- pool stage 1: PCH rows per block, run-flush atomics (batch sorted) -------
__global__ __launch_bounds__(128) void pool_partial(const float* __restrict__ ha,
                                                    const int* __restrict__ batch,
                                                    float* __restrict__ hg) {
    int r0 = blockIdx.x * PCH;
    int f = threadIdx.x;
    int end = min(r0 + PCH, NN);
    int cur = batch[r0];
    float acc = 0.f;
    for (int i = r0; i < end; ++i) {
        int b = batch[i];
        if (b != cur) {
            atomicAdd(&hg[(size_t)cur * D_EMB + f], acc);
            acc = 0.f; cur = b;
        }
        acc += ha[(size_t)i * D_EMB + f];
    }
    atomicAdd(&hg[(size_t)cur * D_EMB + f], acc);
}

// ---------- head MLP: one block (64 threads) per graph on pooled hg ----------
__global__ __launch_bounds__(64) void head_kernel(const float* __restrict__ hg,
                                                  const float* __restrict__ fc1W,
                                                  const float* __restrict__ fc1b,
                                                  const float* __restrict__ fc2W,
                                                  const float* __restrict__ fc2b,
                                                  float* __restrict__ out) {
    int g = blockIdx.x;
    int j = threadIdx.x;  // 0..63
    float h = fc1b[j];
#pragma unroll 8
    for (int k = 0; k < D_EMB; ++k) h += hg[(size_t)g * D_EMB + k] * fc1W[k * 64 + j];
    h = lrelu(h) * fc2W[j];
#pragma unroll
    for (int m = 1; m < 64; m <<= 1) h += __shfl_xor(h, m);
    if (j == 0) out[g] = h + fc2b[0];
}

static inline size_t align256(size_t x) { return (x + 255) & ~(size_t)255; }

extern "C" void kernel_launch(void* const* d_in, const int* in_sizes, int n_in,
                              void* d_out, int out_size, void* d_ws, size_t ws_size,
                              hipStream_t stream) {
    const float* x     = (const float*)d_in[0];
    const int*   ei    = (const int*)d_in[1];
    const int*   batch = (const int*)d_in[2];
    const float* nfc_W = (const float*)d_in[3];
    const float* nfc_b = (const float*)d_in[4];
    const float* gn1_g = (const float*)d_in[5];
    const float* gn1_b = (const float*)d_in[6];
    const float* gc1_W = (const float*)d_in[7];
    const float* gc1_b = (const float*)d_in[8];
    const float* gn2_g = (const float*)d_in[9];
    const float* gn2_b = (const float*)d_in[10];
    const float* gc2_W = (const float*)d_in[11];
    const float* gc2_b = (const float*)d_in[12];
    const float* fc1_W = (const float*)d_in[13];
    const float* fc1_b = (const float*)d_in[14];
    const float* fc2_W = (const float*)d_in[15];
    const float* fc2_b = (const float*)d_in[16];

    char* ws = (char*)d_ws;
    size_t off = 0;
    // cnt + cursor + hg contiguous -> single memset
    int*   cnt    = (int*)(ws + off);   off += (size_t)NN * 4;
    int*   cursor = (int*)(ws + off);   off += (size_t)NN * 4;
    float* hg     = (float*)(ws + off); off += align256((size_t)GG * D_EMB * 4);
    float* dinv   = (float*)(ws + off); off += align256((size_t)NN * 4);
    int*   rowptr = (int*)(ws + off);   off += align256((size_t)(NN + 1) * 4);
    int*   bsum   = (int*)(ws + off);   off += align256((size_t)256 * 4);
    int*   esrc   = (int*)(ws + off);   off += align256((size_t)EE * 4);
    u16*   WtN    = (u16*)(ws + off);   off += align256((size_t)D_H * KP1 * 2);
    u16*   Wt1    = (u16*)(ws + off);   off += align256((size_t)D_H * D_H * 2);
    u16*   Wt2    = (u16*)(ws + off);   off += align256((size_t)D_EMB * D_H * 2);
    u16*   ha1b   = (u16*)(ws + off);   off += align256((size_t)NN * D_H * 2);
    u16*   y1b    = (u16*)(ws + off);   off += align256((size_t)NN * D_H * 2);
    u16*   ha2b   = (u16*)(ws + off);   off += align256((size_t)NN * D_H * 2);
    u16*   y2b    = (u16*)(ws + off);   off += align256((size_t)NN * D_EMB * 2);

    const int* src = ei;
    const int* dst = ei + EE;
    float* out_scores = (float*)d_out;
    float* out_ha     = (float*)d_out + GG;

    const int NB = (NN + 255) / 256;
    const int MB = (NN + 127) / 128;
    const size_t zbytes = (size_t)NN * 8 + (size_t)GG * D_EMB * 4;  // cnt+cursor+hg

    // 1) one memset; CSR build: count -> wide 3-kernel scan(+dinv) -> scatter
    hipMemsetAsync(cnt, 0, zbytes, stream);
    count_kernel<<<(EE + 255) / 256, 256, 0, stream>>>(dst, cnt, EE);
    scan1<<<NB, 256, 0, stream>>>(cnt, rowptr, bsum, dinv, NN);
    scan2<<<1, 256, 0, stream>>>(bsum, NB);
    scan3<<<NB, 256, 0, stream>>>(rowptr, bsum, NN, EE);
    scatter_kernel<<<(EE + 255) / 256, 256, 0, stream>>>(src, dst, rowptr, cursor, esrc, EE);

    // 2) all weight casts in one kernel (x cast fused into GEMM-1)
    cast_all<<<(WN_ELEMS + W1_ELEMS + W2_ELEMS + 255) / 256, 256, 0, stream>>>(
        nfc_W, gc1_W, gc2_W, WtN, Wt1, Wt2);

    // 3) ha1 = lrelu(x @ nfc_W + b)   [N,256] bf16  (A read as fp32, cast in-register)
    gemm_f32a<<<dim3(MB, D_H / 64), 256, 0, stream>>>(
        x, WtN, nfc_b, ha1b, NN, KP1, F_IN, D_H);

    // 4) conv1: y1 = (ha1 @ gc1_W) * dinv[row]; fused agg+LN -> ha2 bf16
    gemm_glds<<<dim3(MB, D_H / 64), 256, 0, stream>>>(
        ha1b, Wt1, dinv, y1b, NN, D_H, D_H);
    agg_ln<D_H, false, true><<<NN / 4, 256, 0, stream>>>(
        y1b, rowptr, esrc, dinv, gc1_b, gn1_g, gn1_b, ha2b, nullptr);

    // 5) conv2: y2 = (ha2 @ gc2_W) * dinv[row]; fused agg+LN+L2 -> out_ha fp32
    gemm_glds<<<dim3(MB, D_EMB / 64), 256, 0, stream>>>(
        ha2b, Wt2, dinv, y2b, NN, D_H, D_EMB);
    agg_ln<D_EMB, true, false><<<NN / 4, 256, 0, stream>>>(
        y2b, rowptr, esrc, dinv, gc2_b, gn2_g, gn2_b, nullptr, out_ha);

    // 6) parallel pool + tiny head
    pool_partial<<<(NN + PCH - 1) / PCH, 128, 0, stream>>>(out_ha, batch, hg);
    head_kernel<<<GG, 64, 0, stream>>>(hg, fc1_W, fc1_b, fc2_W, fc2_b, out_scores);
}